// Round 1
// 533.622 us; speedup vs baseline: 1.0039x; 1.0039x over previous
//
#include <hip/hip_runtime.h>
#include <math.h>

// Problem dims (fixed by reference setup_inputs):
//   video [B=8, C=1024, T=64, W=14, H=14] fp32 ; mu/sigma [N=3] fp32
//   out   [B, C*N] fp32, out[b, c*3+n] = (1/T) * sum_{t,w,h} video[b,c,t,w,h]*f[n,w,h]
#define B_  8
#define C_  1024
#define T_  64
#define W_  14
#define H_  14
#define N_  3
#define WH    (W_ * H_)     // 196 floats per (t) frame
#define WH4   (WH / 4)      // 49 float4 per frame (exact: 196 % 4 == 0)
#define SLAB4 (T_ * WH4)    // 3136 float4 per (b,c) slab (= 49 * 64, exact)

// One wave (64 lanes) per (b,c). ALL 64 lanes stream the [T*WH] slab as a
// flat float4 array: lane l loads element i*64 + l (perfect 1024 B/instr
// coalescing; slab stride 50176 B = 49*1024 is 1024-aligned). The filter
// weight for a loaded element depends on wh4 = idx mod 49, which cycles
// through all residues via r += 15 (mod 49) since gcd(15,49)=1; weights
// live in a 2.35 KB LDS table fsh[3][49] (float4), read as 3 ds_read_b128
// (stride-16B across lanes -> <=2-way bank aliasing, free on CDNA4).
__global__ __launch_bounds__(256) void attn_pool_kernel(
        const float* __restrict__ video,
        const float* __restrict__ mu_x,
        const float* __restrict__ mu_y,
        const float* __restrict__ sigma_x,
        const float* __restrict__ sigma_y,
        float* __restrict__ out)
{
    __shared__ float4 fsh[N_][WH4];   // normalized filters, float4 over wh

    const int wave = threadIdx.x >> 6;
    const int lane = threadIdx.x & 63;
    const int bc   = blockIdx.x * 4 + wave;   // [0, B_*C_)

    // ---- waves 0..2 each build filter n = wave into LDS ----
    if (wave < N_) {
        const int n = wave;
        float w0 = 0.0f, w1 = 0.0f, w2 = 0.0f, w3 = 0.0f;
        if (lane < WH4) {
            // squash params exactly as reference
            const float mux  = 6.5f * (tanhf(mu_x[n]) + 1.0f);   // (W-1)*(tanh+1)/2
            const float muy  = 6.5f * (tanhf(mu_y[n]) + 1.0f);
            const float sgx  = 1.0f / (1.0f + expf(-sigma_x[n]));
            const float sgy  = 1.0f / (1.0f + expf(-sigma_y[n]));
            // sx^2 = exp(2*(1.5 - 2*sig)) = exp(3 - 4*sig)
            const float invx = 1.0f / (expf(3.0f - 4.0f * sgx) + 1e-6f);
            const float invy = 1.0f / (expf(3.0f - 4.0f * sgy) + 1e-6f);
            float wv[4];
#pragma unroll
            for (int j = 0; j < 4; ++j) {
                const int   wh = 4 * lane + j;
                const int   w  = wh / H_;
                const int   h  = wh - w * H_;
                const float dx = (float)w - mux;
                const float dy = (float)h - muy;
                wv[j] = expf(-0.5f * (dx * dx * invx + dy * dy * invy));
            }
            w0 = wv[0]; w1 = wv[1]; w2 = wv[2]; w3 = wv[3];
        }
        // normalize: f /= (sum_{w,h} f + 1e-6), sum via wave butterfly
        float s = w0 + w1 + w2 + w3;
#pragma unroll
        for (int off = 32; off > 0; off >>= 1) s += __shfl_xor(s, off);
        const float norm = 1.0f / (s + 1e-6f);
        if (lane < WH4)
            fsh[n][lane] = make_float4(w0 * norm, w1 * norm, w2 * norm, w3 * norm);
    }
    __syncthreads();

    // ---- stream the slab: 49 iterations, 1 float4 load/lane each ----
    const float4* v4 = (const float4*)video + (size_t)bc * (size_t)SLAB4;
    int r = (lane >= WH4) ? lane - WH4 : lane;   // idx mod 49 at i=0
    float a0 = 0.0f, a1 = 0.0f, a2 = 0.0f;
#pragma unroll 7
    for (int i = 0; i < WH4; ++i) {
        const float4 v  = v4[i * 64 + lane];
        const float4 f0 = fsh[0][r];
        const float4 f1 = fsh[1][r];
        const float4 f2 = fsh[2][r];
        a0 += v.x * f0.x + v.y * f0.y + v.z * f0.z + v.w * f0.w;
        a1 += v.x * f1.x + v.y * f1.y + v.z * f1.z + v.w * f1.w;
        a2 += v.x * f2.x + v.y * f2.y + v.z * f2.z + v.w * f2.w;
        r += 64 - WH4;                 // r = (r + 15) mod 49
        if (r >= WH4) r -= WH4;
    }
    // wave-reduce the 3 accumulators
#pragma unroll
    for (int off = 32; off > 0; off >>= 1) {
        a0 += __shfl_xor(a0, off);
        a1 += __shfl_xor(a1, off);
        a2 += __shfl_xor(a2, off);
    }
    if (lane == 0) {
        float* o = out + (size_t)bc * N_;   // b*C*N + c*N == bc*N
        o[0] = a0 * (1.0f / T_);
        o[1] = a1 * (1.0f / T_);
        o[2] = a2 * (1.0f / T_);
    }
}

extern "C" void kernel_launch(void* const* d_in, const int* in_sizes, int n_in,
                              void* d_out, int out_size, void* d_ws, size_t ws_size,
                              hipStream_t stream) {
    const float* video   = (const float*)d_in[0];
    const float* mu_x    = (const float*)d_in[1];
    const float* mu_y    = (const float*)d_in[2];
    const float* sigma_x = (const float*)d_in[3];
    const float* sigma_y = (const float*)d_in[4];
    float* out = (float*)d_out;

    const int waves  = B_ * C_;        // 8192 (b,c) pairs, one wave each
    const int blocks = waves / 4;      // 4 waves per 256-thread block
    attn_pool_kernel<<<blocks, 256, 0, stream>>>(video, mu_x, mu_y,
                                                 sigma_x, sigma_y, out);
}